// Round 11
// baseline (279.792 us; speedup 1.0000x reference)
//
#include <hip/hip_runtime.h>

typedef __bf16 bf16_t;
typedef __attribute__((ext_vector_type(8))) __bf16 bf16x8;
typedef __attribute__((ext_vector_type(4))) __bf16 bf16x4;
typedef __attribute__((ext_vector_type(4))) float f32x4;

#define M_TOT 8192   // B*T
#define NU    1024   // n_units
#define TSEQ  2048
#define NHEAD 16
#define DHEAD 64
#define BPAD  72
#define QSCALE 0.18033688011f   // 0.125 * log2(e); attention uses exp2

// async 16B/lane global->LDS. LDS dest is wave-uniform base; lane i lands at base + i*16.
__device__ __forceinline__ void gload_lds16(const void* g, void* lds) {
    __builtin_amdgcn_global_load_lds(
        (const __attribute__((address_space(1))) void*)g,
        (__attribute__((address_space(3))) void*)lds,
        16, 0, 0);
}

__device__ __forceinline__ unsigned pk2(float a, float b) {
    const bf16_t x = (bf16_t)a, y = (bf16_t)b;
    return (unsigned)__builtin_bit_cast(unsigned short, x)
         | ((unsigned)__builtin_bit_cast(unsigned short, y) << 16);
}

// Fragment order within a 64x64 operand tile (rows r = m/n/key, cols k):
//   idx = c*512 + s*8 + e;  c = ((r>>4)&3)*2 + (k>>5);  s = ((k>>3)&3)*16 + (r&15);  e = k&7
__device__ __forceinline__ int fidx(int r, int k) {
    return ((((r >> 4) & 3) * 2 + (k >> 5)) << 9)
         + (((((k >> 3) & 3) << 4) + (r & 15)) << 3) + (k & 7);
}
// K ([key][d]) and V^T ([d][key]) frag indices (64x64 tiles over TSEQ)
__device__ __forceinline__ size_t fragK(int bh, int t, int d) {
    return (size_t)bh * (TSEQ * DHEAD) + (size_t)(t >> 6) * 4096 + fidx(t & 63, d);
}
__device__ __forceinline__ size_t fragV(int bh, int t, int d) {
    return (size_t)bh * (TSEQ * DHEAD) + (size_t)(t >> 6) * 4096 + fidx(d, t & 63);
}

// ---------------- converters ----------------
__global__ __launch_bounds__(256)
void cvt_x(const float* __restrict__ x, bf16_t* __restrict__ xb)
{
    const int i = (blockIdx.x * 256 + threadIdx.x) * 8;
    const float4 a = *(const float4*)(x + i);
    const float4 b = *(const float4*)(x + i + 4);
    bf16x8 v;
    v[0] = (bf16_t)a.x; v[1] = (bf16_t)a.y; v[2] = (bf16_t)a.z; v[3] = (bf16_t)a.w;
    v[4] = (bf16_t)b.x; v[5] = (bf16_t)b.y; v[6] = (bf16_t)b.z; v[7] = (bf16_t)b.w;
    *(bf16x8*)(xb + i) = v;
}

// fp32 row-major -> bf16 frag-order tiles, all 5 matrices in ONE launch.
// Coalesced reads: 8 lanes cover one row's 64 cols = 256B contiguous runs.
__global__ __launch_bounds__(256)
void cvt_frag2(const float* __restrict__ x,
               const float* __restrict__ Wq, const float* __restrict__ Wk,
               const float* __restrict__ Wv, const float* __restrict__ Wo,
               bf16_t* __restrict__ Xf, bf16_t* __restrict__ Wf4)
{
    const int bid = blockIdx.x;
    const float* src;
    bf16_t* dst;
    int trow, tcol;
    if (bid < 2048) {                       // x: 128 row-tiles x 16 k-tiles
        src = x;
        dst = Xf + (size_t)bid * 4096;
        trow = bid >> 4; tcol = bid & 15;
    } else {                                // weights: 4 x (16 x 16) tiles
        const int t    = bid - 2048;
        const int wsel = t >> 8;
        const int tt   = t & 255;
        src = (wsel == 0) ? Wq : (wsel == 1 ? Wk : (wsel == 2 ? Wv : Wo));
        dst = Wf4 + (size_t)wsel * NU * NU + (size_t)tt * 4096;
        trow = tt >> 4; tcol = tt & 15;
    }
    const size_t row0 = (size_t)trow * 64;
    const int    col0 = tcol * 64;

    const int tid = threadIdx.x;
#pragma unroll
    for (int h = 0; h < 2; ++h) {
        const int chunk = h * 256 + tid;    // 0..511
        const int r  = chunk >> 3;          // 0..63
        const int k8 = chunk & 7;           // 0..7 (8 bf16 per chunk)
        const float* s = src + (row0 + r) * NU + col0 + k8 * 8;
        const float4 a = *(const float4*)(s);
        const float4 b = *(const float4*)(s + 4);
        bf16x8 v;
        v[0] = (bf16_t)a.x; v[1] = (bf16_t)a.y; v[2] = (bf16_t)a.z; v[3] = (bf16_t)a.w;
        v[4] = (bf16_t)b.x; v[5] = (bf16_t)b.y; v[6] = (bf16_t)b.z; v[7] = (bf16_t)b.w;
        const int idx = ((((r >> 4) & 3) * 2 + (k8 >> 2)) << 9)
                      + (((k8 & 3) * 16 + (r & 15)) << 3);
        *(bf16x8*)(dst + idx) = v;
    }
}

// ---------------- FAST PATH GEMMs ----------------
// v16: T3-minimal single-barrier pipeline, race-free by construction.
// Order per kt: STAGE(S[cur^1], kt+1) -> compute(S[cur]) -> vmcnt(0)+s_barrier.
// kt's STAGE writes the buffer whose last readers (kt-1's compute) all
// passed kt-1's TRAILING barrier before any wave reaches kt's STAGE: no
// write-after-read window (round-8's bug). Loads issued before the ~400cy
// compute phase, so the terminal vmcnt(0) drains an almost-empty queue
// (unlike round-6's STAGE->drain->compute). One barrier + one waitcnt
// per kt — fewer sync points than round 10 (3) and round 6 (2 drains).
// XCD swizzle (v11) + LDS epilogue (v10) retained.
// z=0: Q plain [bh][t][d] scaled QSCALE; z=1: K frag; z=2: V^T frag
__global__ __launch_bounds__(256)
void gemm_qkv_f(const bf16_t* __restrict__ xf,
                const bf16_t* __restrict__ Wqf, const bf16_t* __restrict__ Wkf, const bf16_t* __restrict__ Wvf,
                const float* __restrict__ B0, const float* __restrict__ B1, const float* __restrict__ B2,
                bf16_t* __restrict__ O0, bf16_t* __restrict__ O1, bf16_t* __restrict__ O2)
{
    const int z = blockIdx.z;
    const bf16_t* Wf  = (z == 0) ? Wqf : (z == 1 ? Wkf : Wvf);
    const float* bias = (z == 0) ? B0 : (z == 1 ? B1 : B2);
    bf16_t* out       = (z == 0) ? O0 : (z == 1 ? O1 : O2);
    const float scale = (z == 0) ? QSCALE : 1.0f;

    __shared__ __attribute__((aligned(16))) bf16_t S[2][16384];   // dbuf: [buf] = As(8192) | Bs(8192)

    const int tid = threadIdx.x;
    const int l   = tid & 63;
    const int w   = tid >> 6;
    const int wm  = w >> 1, wn = w & 1;
    const int l15 = l & 15, lq = l >> 4;

    // XCD-chunked bijective remap (512 blocks per z, 512%8==0)
    const int lid = blockIdx.y * 8 + blockIdx.x;
    const int bm  = (lid & 7) * 8 + (lid >> 6);
    const int bn  = (lid >> 3) & 7;

    const bf16_t* gA[4];
    const bf16_t* gB[4];
#pragma unroll
    for (int i = 0; i < 4; ++i) {
        const int cc = w * 4 + i;
        gA[i] = xf + ((size_t)(bm * 2 + (cc >> 3)) * 16) * 4096 + (cc & 7) * 512 + l * 8;
        gB[i] = Wf + ((size_t)(bn * 2 + (cc >> 3)) * 16) * 4096 + (cc & 7) * 512 + l * 8;
    }

#define STAGE_T(b, ktn)                                                          \
    do {                                                                         \
        _Pragma("unroll")                                                        \
        for (int i_ = 0; i_ < 4; ++i_) {                                         \
            const int cc_ = w * 4 + i_;                                          \
            gload_lds16(gA[i_] + (size_t)(ktn) * 4096, &S[b][cc_ * 512]);        \
            gload_lds16(gB[i_] + (size_t)(ktn) * 4096, &S[b][8192 + cc_ * 512]); \
        }                                                                        \
    } while (0)

    f32x4 acc[4][4] = {};

    // prologue: stage tile 0, drain, sync
    STAGE_T(0, 0);
    asm volatile("s_waitcnt vmcnt(0)\n\ts_barrier" ::: "memory");

    for (int kt = 0; kt < 16; ++kt) {
        const int cur = kt & 1;
        // issue next tile's loads into the OTHER buffer; latency hides
        // under this iteration's compute
        if (kt < 15) STAGE_T(cur ^ 1, kt + 1);

        const bf16_t* Asb = &S[cur][0];
        const bf16_t* Bsb = &S[cur][8192];
#pragma unroll
        for (int ks = 0; ks < 2; ++ks) {
            bf16x8 af[4], bfr[4];
#pragma unroll
            for (int mt = 0; mt < 4; ++mt)
                af[mt] = *(const bf16x8*)&Asb[wm * 4096 + (mt * 2 + ks) * 512 + l * 8];
#pragma unroll
            for (int nt = 0; nt < 4; ++nt)
                bfr[nt] = *(const bf16x8*)&Bsb[wn * 4096 + (nt * 2 + ks) * 512 + l * 8];
#pragma unroll
            for (int mt = 0; mt < 4; ++mt)
#pragma unroll
                for (int nt = 0; nt < 4; ++nt)
                    acc[mt][nt] = __builtin_amdgcn_mfma_f32_16x16x32_bf16(af[mt], bfr[nt], acc[mt][nt], 0, 0, 0);
        }
        // next tile landed + all waves done reading S[cur] -> next iter may
        // compute from S[cur^1] and stage into S[cur]. Single sync point.
        asm volatile("s_waitcnt vmcnt(0)\n\ts_barrier" ::: "memory");
    }
#undef STAGE_T

    // ---- epilogue: per-wave private LDS quadrant, same-wave round trip ----
    // Final trailing barrier guarantees all waves done with S before reuse.
    bf16_t* Cs = &S[0][w * 4096];
#pragma unroll
    for (int nt = 0; nt < 4; ++nt) {
        const int gn = bn * 128 + wn * 64 + nt * 16 + l15;
        const float bv = bias[gn];
        const int kp = nt * 16 + l15;              // local col (d) 0..63
#pragma unroll
        for (int mt = 0; mt < 4; ++mt) {
#pragma unroll
            for (int r = 0; r < 4; ++r) {
                const int rp = mt * 16 + lq * 4 + r;   // local row (t) 0..63
                const float v = (acc[mt][nt][r] + bv) * scale;
                int idx;
                if (z == 0)      idx = rp * 64 + kp;       // plain [t][d]
                else if (z == 1) idx = fidx(rp, kp);       // K frag
                else             idx = fidx(kp, rp);       // V^T frag
                Cs[idx] = (bf16_t)v;
            }
        }
    }
    // wave-uniform output base
    const int bm2 = bm * 2 + wm;          // global t-tile index (0..127)
    const int b   = bm2 >> 5;             // 32 t-tiles per batch elem
    const int hh  = bn * 2 + wn;          // head
    const int bh  = b * NHEAD + hh;
    size_t obase;
    if (z == 0) obase = ((size_t)bh * TSEQ + (size_t)(bm2 & 31) * 64) * DHEAD;
    else        obase = ((size_t)bh * 32 + (bm2 & 31)) * 4096;
    // DS pipe is in-order per wave (same-wave write->read, v5 Ps precedent)
#pragma unroll
    for (int c = 0; c < 8; ++c) {
        const bf16x8 cv = *(const bf16x8*)&Cs[c * 512 + l * 8];
        *(bf16x8*)(out + obase + c * 512 + l * 8) = cv;
    }
}

// out-proj: A = ctx frag-order [b][h][t>>6][4096], B = Wo frag-order; fp32 out
// Same v16 single-barrier trailing-wait pipeline + XCD swizzle.
__global__ __launch_bounds__(256)
void gemm_out_f(const bf16_t* __restrict__ cf, const bf16_t* __restrict__ Wof,
                const float* __restrict__ bo, float* __restrict__ out)
{
    __shared__ __attribute__((aligned(16))) bf16_t S[2][16384];   // dbuf: As | Bs

    const int tid = threadIdx.x;
    const int l   = tid & 63;
    const int w   = tid >> 6;
    const int wm  = w >> 1, wn = w & 1;
    const int l15 = l & 15, lq = l >> 4;

    // XCD-chunked bijective remap (512 blocks, 512%8==0)
    const int lid = blockIdx.y * 8 + blockIdx.x;
    const int bm  = (lid & 7) * 8 + (lid >> 6);
    const int bn  = (lid >> 3) & 7;
    const int b   = bm >> 4;

    const bf16_t* gB[4];
    size_t aoff[4];
#pragma unroll
    for (int i = 0; i < 4; ++i) {
        const int cc = w * 4 + i;
        aoff[i] = (((size_t)b * 16) * 32 + (bm & 15) * 2 + (cc >> 3)) * 4096 + (cc & 7) * 512 + l * 8;
        gB[i] = Wof + ((size_t)(bn * 2 + (cc >> 3)) * 16) * 4096 + (cc & 7) * 512 + l * 8;
    }

#define STAGE_O(bf, ktn)                                                                  \
    do {                                                                                  \
        _Pragma("unroll")                                                                 \
        for (int i_ = 0; i_ < 4; ++i_) {                                                  \
            const int cc_ = w * 4 + i_;                                                   \
            gload_lds16(cf + aoff[i_] + (size_t)(ktn) * (32 * 4096), &S[bf][cc_ * 512]);  \
            gload_lds16(gB[i_] + (size_t)(ktn) * 4096, &S[bf][8192 + cc_ * 512]);         \
        }                                                                                 \
    } while (0)

    f32x4 acc[4][4] = {};

    STAGE_O(0, 0);
    asm volatile("s_waitcnt vmcnt(0)\n\ts_barrier" ::: "memory");

    for (int kt = 0; kt < 16; ++kt) {
        const int cur = kt & 1;
        if (kt < 15) STAGE_O(cur ^ 1, kt + 1);

        const bf16_t* Asb = &S[cur][0];
        const bf16_t* Bsb = &S[cur][8192];
#pragma unroll
        for (int ks = 0; ks < 2; ++ks) {
            bf16x8 af[4], bfr[4];
#pragma unroll
            for (int mt = 0; mt < 4; ++mt)
                af[mt] = *(const bf16x8*)&Asb[wm * 4096 + (mt * 2 + ks) * 512 + l * 8];
#pragma unroll
            for (int nt = 0; nt < 4; ++nt)
                bfr[nt] = *(const bf16x8*)&Bsb[wn * 4096 + (nt * 2 + ks) * 512 + l * 8];
#pragma unroll
            for (int mt = 0; mt < 4; ++mt)
#pragma unroll
                for (int nt = 0; nt < 4; ++nt)
                    acc[mt][nt] = __builtin_amdgcn_mfma_f32_16x16x32_bf16(af[mt], bfr[nt], acc[mt][nt], 0, 0, 0);
        }
        asm volatile("s_waitcnt vmcnt(0)\n\ts_barrier" ::: "memory");
    }
#undef STAGE_O

#pragma unroll
    for (int nt = 0; nt < 4; ++nt) {
        const int gn = bn * 128 + wn * 64 + nt * 16 + l15;
        const float bv = bo[gn];
#pragma unroll
        for (int mt = 0; mt < 4; ++mt) {
            const int rb = bm * 128 + wm * 64 + mt * 16 + lq * 4;
#pragma unroll
            for (int r = 0; r < 4; ++r)
                out[(size_t)(rb + r) * NU + gn] = acc[mt][nt][r] + bv;
        }
    }
}

// ---------------- FALLBACK GEMMs (W fp32 reg-prefetch) ----------------
__global__ __launch_bounds__(256)
void gemm_qkv(const bf16_t* __restrict__ A,
              const float* __restrict__ W0, const float* __restrict__ W1, const float* __restrict__ W2,
              const float* __restrict__ B0, const float* __restrict__ B1, const float* __restrict__ B2,
              bf16_t* __restrict__ O0, bf16_t* __restrict__ O1, bf16_t* __restrict__ O2)
{
    const int z = blockIdx.z;
    const float* W    = (z == 0) ? W0 : (z == 1 ? W1 : W2);
    const float* bias = (z == 0) ? B0 : (z == 1 ? B1 : B2);
    bf16_t* out       = (z == 0) ? O0 : (z == 1 ? O1 : O2);
    const float scale = (z == 0) ? QSCALE : 1.0f;

    __shared__ __attribute__((aligned(16))) bf16_t As[128 * 64];
    __shared__ __attribute__((aligned(16))) bf16_t Bs[128 * BPAD];

    const int tid = threadIdx.x;
    const int l = tid & 63, w = tid >> 6;
    const int wm = w >> 1, wn = w & 1;
    const int l15 = l & 15, lq = l >> 4;
    const int bm = blockIdx.y, bn = blockIdx.x;
    const int srow = l >> 3, scol = (l & 7) * 8;
    const bf16_t* gA = A + (size_t)(bm * 128 + srow) * NU + scol;
    const int sr = tid >> 4, sc = (tid & 15) * 4;
    const float* gW = W + (size_t)(bn * 128 + sr) * NU + sc;

    f32x4 acc[4][4] = {};
    float4 wreg[8];
#pragma unroll
    for (int i = 0; i < 8; ++i) wreg[i] = *(const float4*)(gW + (size_t)(i * 16) * NU);

    for (int k0 = 0; k0 < NU; k0 += 64) {
#pragma unroll
        for (int i = 0; i < 4; ++i) {
            const int r0 = i * 32 + w * 8;
            gload_lds16(gA + (size_t)r0 * NU + k0, &As[r0 * 64]);
        }
#pragma unroll
        for (int i = 0; i < 8; ++i) {
            bf16x4 wb;
            wb[0] = (bf16_t)wreg[i].x; wb[1] = (bf16_t)wreg[i].y;
            wb[2] = (bf16_t)wreg[i].z; wb[3] = (bf16_t)wreg[i].w;
            *(bf16x4*)&Bs[(i * 16 + sr) * BPAD + sc] = wb;
        }
        __syncthreads();
        if (k0 + 64 < NU) {
#pragma unroll
            for (int i = 0; i < 8; ++i)
                wreg[i] = *(const float4*)(gW + (size_t)(i * 16) * NU + k0 + 64);
        }
#pragma unroll
        for (int ks = 0; ks < 2; ++ks) {
            bf16x8 af[4], bfr[4];
#pragma unroll
            for (int mt = 0; mt < 4; ++mt)
                af[mt] = *(const bf16x8*)&As[(wm * 64 + mt * 16 + l15) * 64 + ks * 32 + lq * 8];
#pragma unroll
            for (int nt = 0; nt < 4; ++nt)
                bfr[nt] = *(const bf16x8*)&Bs[(wn * 64 + nt * 16 + l15) * BPAD + ks * 32 + lq * 8];
#pragma unroll
            for (int mt = 0; mt < 4; ++mt)
#pragma unroll
                for (int nt = 0; nt < 4; ++nt)
                    acc[mt][nt] = __builtin_amdgcn_mfma_f32_16x16x32_bf16(af[mt], bfr[nt], acc[mt][nt], 0, 0, 0);
        }
        __syncthreads();
    }

#pragma unroll
    for (int nt = 0; nt < 4; ++nt) {
        const int gn = bn * 128 + wn * 64 + nt * 16 + l15;
        const float bv = bias[gn];
#pragma unroll
        for (int mt = 0; mt < 4; ++mt) {
            const int rb = bm * 128 + wm * 64 + mt * 16 + lq * 4;
#pragma unroll
            for (int r = 0; r < 4; ++r) {
                const int gm = rb + r;
                const float v = (acc[mt][nt][r] + bv) * scale;
                const int b = gm >> 11, t = gm & (TSEQ - 1);
                const int h = gn >> 6,  d = gn & 63;
                const int bh = b * NHEAD + h;
                if (z == 0)      out[((size_t)bh * TSEQ + t) * DHEAD + d] = (bf16_t)v;
                else if (z == 1) out[fragK(bh, t, d)] = (bf16_t)v;
                else             out[fragV(bh, t, d)] = (bf16_t)v;
            }
        }
    }
}

__global__ __launch_bounds__(256)
void gemm_out(const bf16_t* __restrict__ ctx, const float* __restrict__ Wo,
              const float* __restrict__ bo, float* __restrict__ out)
{
    __shared__ __attribute__((aligned(16))) bf16_t As[128 * 64];
    __shared__ __attribute__((aligned(16))) bf16_t Bs[128 * BPAD];

    const int tid = threadIdx.x;
    const int l = tid & 63, w = tid >> 6;
    const int wm = w >> 1, wn = w & 1;
    const int l15 = l & 15, lq = l >> 4;
    const int bm = blockIdx.y, bn = blockIdx.x;
    const int srow = l >> 3, scol = (l & 7) * 8;
    const int b = bm >> 4;
    const bf16_t* gA = ctx + (size_t)b * (NHEAD * TSEQ * DHEAD)
                           + (size_t)((bm & 15) * 128 + srow) * DHEAD + scol;
    const int sr = tid >> 4, sc = (tid & 15) * 4;
    const float* gW = Wo + (size_t)(bn * 128 + sr) * NU + sc;

    f32x4 acc[4][4] = {};
    float4 wreg[8];
#pragma unroll
    for (int i = 0; i < 8; ++i) wreg[i] = *(const float4*)(gW + (size_t)(i * 16) * NU);

    for (int k0 = 0; k0 < NU; k0 += 64) {
#pragma unroll
        for (int i = 0; i < 4; ++i) {
            const int r0 = i * 32 + w * 8;
            gload_lds16(gA + (size_t)r0 * DHEAD + ((size_t)k0 << 11), &As[r0 * 64]);
        }
#pragma unroll
        for (int i = 0; i < 8; ++i) {
            bf16x4 wb;
            wb[0] = (bf16_t)wreg[i].x; wb[1] = (bf16_t)wreg[i].y;
            wb[2] = (bf16_t)wreg[i].z; wb[3] = (bf16_t)wreg[i].w;
            *(bf16x4*)&Bs[(i * 16 + sr) * BPAD + sc] = wb;
        }
        __syncthreads();
        if (k0 + 64 < NU) {
#pragma unroll
            for (int i = 0; i < 8; ++i)
                wreg[i] = *(const float4*)(gW + (size_t)(i * 16) * NU + k0 + 64);
        }
#pragma unroll
        for (int ks = 0; ks < 2; ++ks) {
            bf16x8 af[4], bfr[4];
#pragma unroll
            for (int mt = 0; mt < 4; ++mt)
                af[mt] = *(const bf16x8*)&As[(wm * 64 + mt * 16 + l15) * 64 + ks * 32 + lq * 8];
#pragma unroll
            for (int nt = 0; nt < 4; ++nt)
                bfr[nt] = *(const bf16x8*)&Bs[(wn * 64 + nt * 16 + l15) * BPAD + ks * 32 + lq * 8];
#pragma unroll
            for (int mt = 0; mt < 4; ++mt)
#pragma unroll
                for (int nt = 0; nt < 4; ++nt)
                    acc[mt][nt] = __builtin_amdgcn_mfma_f32_16x16x32_bf16(af[mt], bfr[nt], acc[mt][nt], 0, 0, 0);
        }
        __syncthreads();
    }

#pragma unroll
    for (int nt = 0; nt < 4; ++nt) {
        const int gn = bn * 128 + wn * 64 + nt * 16 + l15;
        const float bv = bo[gn];
#pragma unroll
        for (int mt = 0; mt < 4; ++mt) {
            const int rb = bm * 128 + wm * 64 + mt * 16 + lq * 4;
#pragma unroll
            for (int r = 0; r < 4; ++r)
                out[(size_t)(rb + r) * NU + gn] = acc[mt][nt][r] + bv;
        }
    }
}

// ---------------- Flash attention v5: barrier-free, K/V frag global->VGPR ----------------
// Measured best of four variants (85-87us, ~885 TF effective = the plain-HIP
// 2-barrier structure ceiling). Keep frozen.
template <bool FRAGOUT>
__global__ __launch_bounds__(256, 3)
void attn_fwd(const bf16_t* __restrict__ Q, const bf16_t* __restrict__ Kf,
              const bf16_t* __restrict__ Vf, bf16_t* __restrict__ Cw)
{
    __shared__ __attribute__((aligned(16))) bf16_t Ps[4][4 * 512];   // 16 KB

    const int tid = threadIdx.x;
    const int l   = tid & 63;
    const int w   = tid >> 6;
    const int l15 = l & 15, lq = l >> 4;

    const int id = blockIdx.x;
    const int bh = (id & 7) * 8 + ((id >> 3) & 7);   // 8 bh per XCD (id%8 RR)
    const int qt = id >> 6;                          // 16 q-tiles
    const int q0 = qt * 128 + w * 32;

    const bf16_t* Qb = Q  + (size_t)bh * TSEQ * DHEAD;
    const bf16_t* Kb = Kf + (size_t)bh * TSEQ * DHEAD + l * 8;
    const bf16_t* Vb = Vf + (size_t)bh * TSEQ * DHEAD + l * 8;

    bf16x8 qf[2][2];
#pragma unroll
    for (int mt = 0; mt < 2; ++mt)
#pragma unroll
        for (int ks = 0; ks < 2; ++ks)
            qf[mt][ks] = *(const bf16x8*)(Qb + (size_t)(q0 + mt * 16 + l15) * DHEAD + ks * 32 + lq * 8);

    bf16x8 ones;
#pragma unroll
    for (int j = 0; j < 8; ++j) ones[j] = (bf16_t)1.0f;

    f32x4 cacc[2][4] = {};   // ctx^T: q = mt*16+l15, d = dt*16+lq*4+r
    f32x4 lacc[2] = {};      // MFMA row-sums

    int* PsI = (int*)&Ps[w][0];

    for (int kt = 0; kt < TSEQ / 64; ++kt) {
        const bf16_t* kb = Kb + kt * 4096;
        const bf16_t* vb = Vb + kt * 4096;

        // K fragments: direct global->VGPR (frag-order, coalesced 16B/lane)
        bf16x8 kf[8];
#pragma unroll
        for (int c = 0; c < 8; ++c) kf[c] = *(const bf16x8*)(kb + c * 512);

        // S^T[key][q] (Q pre-scaled by 0.125*log2e)
        f32x4 st[4][2] = {};
#pragma unroll
        for (int ks = 0; ks < 2; ++ks)
#pragma unroll
            for (int nt = 0; nt < 4; ++nt)
#pragma unroll
                for (int mt = 0; mt < 2; ++mt)
                    st[nt][mt] = __builtin_amdgcn_mfma_f32_16x16x32_bf16(kf[nt * 2 + ks], qf[mt][ks], st[nt][mt], 0, 0, 0);

        // P = 2^(S^T) -> pack pairs -> per-wave frag-order Ps (B-operand layout)
#pragma unroll
        for (int nt = 0; nt < 4; ++nt)
#pragma unroll
            for (int mt = 0; mt < 2; ++mt) {
                const float p0 = __builtin_amdgcn_exp2f(st[nt][mt][0]);
                const float p1 = __builtin_amdgcn_exp2f(st[nt][mt][1]);
                const float p2 = __builtin_amdgcn_exp2f(st[nt][mt][2]);
                const float p3 = __builtin_amdgcn_exp2f(st[nt][mt][3]);
                const int base = (mt * 2 + (nt >> 1)) * 256
                               + ((nt & 1) * 2 + (lq >> 1)) * 64 + l15 * 4;
                PsI[base + ((lq * 2 + 0) & 3)] = (int)pk2(p0, p1);
                PsI[base + ((lq * 2 + 1) & 3)] = (int)pk2(p2, p3);
            }

        // V fragments issued here: latency drains under the Ps lgkm wait
        bf16x8 vf[8];
#pragma unroll
        for (int c = 0; c < 8; ++c) vf[c] = *(const bf16x8*)(vb + c * 512);

        // ctx^T += V^T P^T; lsum += ones · P^T (same-wave LDS round trip, no barrier)
#pragma unroll
        for (int kv = 0; kv < 2; ++kv) {
            bf16x8 pf[2];
#pragma unroll
            for (int mt = 0; mt < 2; ++mt)
                pf[mt] = *(const bf16x8*)&Ps[w][(mt * 2 + kv) * 512 + l * 8];
#pragma unroll
            for (int mt = 0; mt < 2; ++mt) {
                lacc[mt] = __builtin_amdgcn_mfma_f32_16x16x32_bf16(ones, pf[mt], lacc[mt], 0, 0, 0);
#pragma unroll
                for (int dt = 0; dt < 4; ++dt)
                    cacc[mt][dt] = __builtin_amdgcn_mfma_f32_16x16x32_bf16(vf[dt * 2 + kv], pf[mt], cacc[mt][dt], 0, 0, 0);
            }
        }
    }

#pragma unroll
    for (int mt = 0; mt < 2; ++mt) {
        const float inv = 1.0f / lacc[mt][0];
        const int q = q0 + mt * 16 + l15;
#pragma unroll
        for (int dt = 0; dt < 4; ++dt) {
            bf16x4 cv;
#pragma unroll
            for (int r = 0; r < 4; ++r) cv[r] = (bf16_t)(cacc[mt][dt][r] * inv);
            if (FRAGOUT) {
                const int qr = q & 63;
                const size_t base = ((size_t)bh * 32 + (q >> 6)) * 4096;
                const int d0 = dt * 16 + lq * 4;
                const int addr = ((((qr >> 4) & 3) * 2 + (d0 >> 5)) << 9)
                               + (((((d0 >> 3) & 3) << 4) + (qr & 15)) << 3) + (d0 & 7);
                *(bf16x4*)&Cw[base + addr] = cv;
            } else {
                *(bf16x4*)&Cw[((size_t)bh * TSEQ + q) * DHEAD + dt * 16 + lq * 4] = cv;
            }
        }
    }
}

__global__ void diag_fill(float* out, int n, float val)
{
    int i = blockIdx.x * blockDim.x + threadIdx.x;
    if (i < n) out[i] = val;
}

extern "C" void kernel_launch(void* const* d_in, const int* in_sizes, int n_in,
                              void* d_out, int out_size, void* d_ws, size_t ws_size,
                              hipStream_t stream)
{
    const float* x  = (const float*)d_in[0];
    const float* Wq = (const float*)d_in[1];
    const float* bq = (const float*)d_in[2];
    const float* Wk = (const float*)d_in[3];
    const float* bk = (const float*)d_in[4];
    const float* Wv = (const float*)d_in[5];
    const float* bv = (const float*)d_in[6];
    const float* Wo = (const float*)d_in[7];
    const float* bo = (const float*)d_in[8];

    const size_t SLOT = (size_t)M_TOT * NU;
    const size_t WSZ  = (size_t)NU * NU;
    const size_t need_fast = (2 * SLOT + 4 * WSZ) * sizeof(bf16_t);   // 40 MB
    const size_t need_min  = 2 * SLOT * sizeof(bf16_t);               // 32 MB

    bf16_t* Qw = (bf16_t*)d_out;            // [bh][t][d], pre-scaled
    bf16_t* Kw = Qw + SLOT;                 // frag-order

    if (ws_size >= need_fast) {
        bf16_t* Xf  = (bf16_t*)d_ws;
        bf16_t* Vt  = Xf + SLOT;
        bf16_t* Wf4 = Vt + SLOT;            // Wq,Wk,Wv,Wo frag-order, contiguous
        bf16_t* Cf  = Xf;                   // ctx frag reuses x slot

        cvt_frag2<<<dim3(2048 + 4 * 256), 256, 0, stream>>>(x, Wq, Wk, Wv, Wo, Xf, Wf4);
        gemm_qkv_f<<<dim3(NU / 128, M_TOT / 128, 3), 256, 0, stream>>>(
            Xf, Wf4, Wf4 + WSZ, Wf4 + 2 * WSZ, bq, bk, bv, Qw, Kw, Vt);
        attn_fwd<true><<<dim3(1024), 256, 0, stream>>>(Qw, Kw, Vt, Cf);
        gemm_out_f<<<dim3(NU / 128, M_TOT / 128), 256, 0, stream>>>(Cf, Wf4 + 3 * WSZ, bo, (float*)d_out);
    } else if (ws_size >= need_min) {
        bf16_t* Xb = (bf16_t*)d_ws;
        bf16_t* Vt = Xb + SLOT;
        bf16_t* Cw = Xb;
        cvt_x<<<dim3(M_TOT * NU / (256 * 8)), 256, 0, stream>>>(x, Xb);
        gemm_qkv<<<dim3(NU / 128, M_TOT / 128, 3), 256, 0, stream>>>(
            Xb, Wq, Wk, Wv, bq, bk, bv, Qw, Kw, Vt);
        attn_fwd<false><<<dim3(1024), 256, 0, stream>>>(Qw, Kw, Vt, Cw);
        gemm_out<<<dim3(NU / 128, M_TOT / 128), 256, 0, stream>>>(Cw, Wo, bo, (float*)d_out);
    } else {
        diag_fill<<<(out_size + 255) / 256, 256, 0, stream>>>((float*)d_out, out_size, 9.0f);
    }
}

// Round 12
// 264.568 us; speedup vs baseline: 1.0575x; 1.0575x over previous
//
#include <hip/hip_runtime.h>

typedef __bf16 bf16_t;
typedef __attribute__((ext_vector_type(8))) __bf16 bf16x8;
typedef __attribute__((ext_vector_type(4))) __bf16 bf16x4;
typedef __attribute__((ext_vector_type(4))) float f32x4;

#define M_TOT 8192   // B*T
#define NU    1024   // n_units
#define TSEQ  2048
#define NHEAD 16
#define DHEAD 64
#define BPAD  72
#define QSCALE 0.18033688011f   // 0.125 * log2(e); attention uses exp2

// async 16B/lane global->LDS. LDS dest is wave-uniform base; lane i lands at base + i*16.
__device__ __forceinline__ void gload_lds16(const void* g, void* lds) {
    __builtin_amdgcn_global_load_lds(
        (const __attribute__((address_space(1))) void*)g,
        (__attribute__((address_space(3))) void*)lds,
        16, 0, 0);
}

__device__ __forceinline__ unsigned pk2(float a, float b) {
    const bf16_t x = (bf16_t)a, y = (bf16_t)b;
    return (unsigned)__builtin_bit_cast(unsigned short, x)
         | ((unsigned)__builtin_bit_cast(unsigned short, y) << 16);
}

// Fragment order within a 64x64 operand tile (rows r = m/n/key, cols k):
//   idx = c*512 + s*8 + e;  c = ((r>>4)&3)*2 + (k>>5);  s = ((k>>3)&3)*16 + (r&15);  e = k&7
__device__ __forceinline__ int fidx(int r, int k) {
    return ((((r >> 4) & 3) * 2 + (k >> 5)) << 9)
         + (((((k >> 3) & 3) << 4) + (r & 15)) << 3) + (k & 7);
}
// K ([key][d]) and V^T ([d][key]) frag indices (64x64 tiles over TSEQ)
__device__ __forceinline__ size_t fragK(int bh, int t, int d) {
    return (size_t)bh * (TSEQ * DHEAD) + (size_t)(t >> 6) * 4096 + fidx(t & 63, d);
}
__device__ __forceinline__ size_t fragV(int bh, int t, int d) {
    return (size_t)bh * (TSEQ * DHEAD) + (size_t)(t >> 6) * 4096 + fidx(d, t & 63);
}

// ---------------- converters ----------------
__global__ __launch_bounds__(256)
void cvt_x(const float* __restrict__ x, bf16_t* __restrict__ xb)
{
    const int i = (blockIdx.x * 256 + threadIdx.x) * 8;
    const float4 a = *(const float4*)(x + i);
    const float4 b = *(const float4*)(x + i + 4);
    bf16x8 v;
    v[0] = (bf16_t)a.x; v[1] = (bf16_t)a.y; v[2] = (bf16_t)a.z; v[3] = (bf16_t)a.w;
    v[4] = (bf16_t)b.x; v[5] = (bf16_t)b.y; v[6] = (bf16_t)b.z; v[7] = (bf16_t)b.w;
    *(bf16x8*)(xb + i) = v;
}

// fp32 row-major -> bf16 frag-order tiles, all 5 matrices in ONE launch.
// Coalesced reads: 8 lanes cover one row's 64 cols = 256B contiguous runs.
__global__ __launch_bounds__(256)
void cvt_frag2(const float* __restrict__ x,
               const float* __restrict__ Wq, const float* __restrict__ Wk,
               const float* __restrict__ Wv, const float* __restrict__ Wo,
               bf16_t* __restrict__ Xf, bf16_t* __restrict__ Wf4)
{
    const int bid = blockIdx.x;
    const float* src;
    bf16_t* dst;
    int trow, tcol;
    if (bid < 2048) {                       // x: 128 row-tiles x 16 k-tiles
        src = x;
        dst = Xf + (size_t)bid * 4096;
        trow = bid >> 4; tcol = bid & 15;
    } else {                                // weights: 4 x (16 x 16) tiles
        const int t    = bid - 2048;
        const int wsel = t >> 8;
        const int tt   = t & 255;
        src = (wsel == 0) ? Wq : (wsel == 1 ? Wk : (wsel == 2 ? Wv : Wo));
        dst = Wf4 + (size_t)wsel * NU * NU + (size_t)tt * 4096;
        trow = tt >> 4; tcol = tt & 15;
    }
    const size_t row0 = (size_t)trow * 64;
    const int    col0 = tcol * 64;

    const int tid = threadIdx.x;
#pragma unroll
    for (int h = 0; h < 2; ++h) {
        const int chunk = h * 256 + tid;    // 0..511
        const int r  = chunk >> 3;          // 0..63
        const int k8 = chunk & 7;           // 0..7 (8 bf16 per chunk)
        const float* s = src + (row0 + r) * NU + col0 + k8 * 8;
        const float4 a = *(const float4*)(s);
        const float4 b = *(const float4*)(s + 4);
        bf16x8 v;
        v[0] = (bf16_t)a.x; v[1] = (bf16_t)a.y; v[2] = (bf16_t)a.z; v[3] = (bf16_t)a.w;
        v[4] = (bf16_t)b.x; v[5] = (bf16_t)b.y; v[6] = (bf16_t)b.z; v[7] = (bf16_t)b.w;
        const int idx = ((((r >> 4) & 3) * 2 + (k8 >> 2)) << 9)
                      + (((k8 & 3) * 16 + (r & 15)) << 3);
        *(bf16x8*)(dst + idx) = v;
    }
}

// ---------------- FAST PATH GEMMs (FINAL = round-6 v11 configuration) ----------------
// Pipelining post-mortem (rounds 7-11): vmcnt(8)-top pipeline = 266.4us but
// RACY (write-after-read hole, bit at 256^2); +trailing barrier = 274.2;
// single-barrier trailing-drain = 279.8. This plain 2-syncthreads loop =
// 270.8us, best SAFE config: the implicit cross-block overlap (4-6
// blocks/CU) already hides what source pipelining would add (the guide's
// m99/m131-141 lesson, reproduced here). Keep: XCD swizzle (+14.6us),
// per-wave LDS epilogue (+5.4us), fused converter (+6us).
// z=0: Q plain [bh][t][d] scaled QSCALE; z=1: K frag; z=2: V^T frag
__global__ __launch_bounds__(256)
void gemm_qkv_f(const bf16_t* __restrict__ xf,
                const bf16_t* __restrict__ Wqf, const bf16_t* __restrict__ Wkf, const bf16_t* __restrict__ Wvf,
                const float* __restrict__ B0, const float* __restrict__ B1, const float* __restrict__ B2,
                bf16_t* __restrict__ O0, bf16_t* __restrict__ O1, bf16_t* __restrict__ O2)
{
    const int z = blockIdx.z;
    const bf16_t* Wf  = (z == 0) ? Wqf : (z == 1 ? Wkf : Wvf);
    const float* bias = (z == 0) ? B0 : (z == 1 ? B1 : B2);
    bf16_t* out       = (z == 0) ? O0 : (z == 1 ? O1 : O2);
    const float scale = (z == 0) ? QSCALE : 1.0f;

    __shared__ __attribute__((aligned(16))) bf16_t S[16384];   // As | Bs, reused as C-staging
    bf16_t* As = S;
    bf16_t* Bs = S + 8192;

    const int tid = threadIdx.x;
    const int l   = tid & 63;
    const int w   = tid >> 6;
    const int wm  = w >> 1, wn = w & 1;
    const int l15 = l & 15, lq = l >> 4;

    // XCD-chunked bijective remap (512 blocks per z, 512%8==0)
    const int lid = blockIdx.y * 8 + blockIdx.x;
    const int bm  = (lid & 7) * 8 + (lid >> 6);
    const int bn  = (lid >> 3) & 7;

    const bf16_t* gA[4];
    const bf16_t* gB[4];
#pragma unroll
    for (int i = 0; i < 4; ++i) {
        const int cc = w * 4 + i;
        gA[i] = xf + ((size_t)(bm * 2 + (cc >> 3)) * 16) * 4096 + (cc & 7) * 512 + l * 8;
        gB[i] = Wf + ((size_t)(bn * 2 + (cc >> 3)) * 16) * 4096 + (cc & 7) * 512 + l * 8;
    }

    f32x4 acc[4][4] = {};

    for (int kt = 0; kt < 16; ++kt) {
#pragma unroll
        for (int i = 0; i < 4; ++i) {
            const int cc = w * 4 + i;
            gload_lds16(gA[i] + (size_t)kt * 4096, &As[cc * 512]);
            gload_lds16(gB[i] + (size_t)kt * 4096, &Bs[cc * 512]);
        }
        __syncthreads();
#pragma unroll
        for (int ks = 0; ks < 2; ++ks) {
            bf16x8 af[4], bfr[4];
#pragma unroll
            for (int mt = 0; mt < 4; ++mt)
                af[mt] = *(const bf16x8*)&As[wm * 4096 + (mt * 2 + ks) * 512 + l * 8];
#pragma unroll
            for (int nt = 0; nt < 4; ++nt)
                bfr[nt] = *(const bf16x8*)&Bs[wn * 4096 + (nt * 2 + ks) * 512 + l * 8];
#pragma unroll
            for (int mt = 0; mt < 4; ++mt)
#pragma unroll
                for (int nt = 0; nt < 4; ++nt)
                    acc[mt][nt] = __builtin_amdgcn_mfma_f32_16x16x32_bf16(af[mt], bfr[nt], acc[mt][nt], 0, 0, 0);
        }
        __syncthreads();
    }
    // final barrier above guarantees all waves are done reading As/Bs

    // ---- epilogue: per-wave private LDS quadrant, same-wave round trip ----
    bf16_t* Cs = &S[w * 4096];
#pragma unroll
    for (int nt = 0; nt < 4; ++nt) {
        const int gn = bn * 128 + wn * 64 + nt * 16 + l15;
        const float bv = bias[gn];
        const int kp = nt * 16 + l15;              // local col (d) 0..63
#pragma unroll
        for (int mt = 0; mt < 4; ++mt) {
#pragma unroll
            for (int r = 0; r < 4; ++r) {
                const int rp = mt * 16 + lq * 4 + r;   // local row (t) 0..63
                const float v = (acc[mt][nt][r] + bv) * scale;
                int idx;
                if (z == 0)      idx = rp * 64 + kp;       // plain [t][d]
                else if (z == 1) idx = fidx(rp, kp);       // K frag
                else             idx = fidx(kp, rp);       // V^T frag
                Cs[idx] = (bf16_t)v;
            }
        }
    }
    // wave-uniform output base
    const int bm2 = bm * 2 + wm;          // global t-tile index (0..127)
    const int b   = bm2 >> 5;             // 32 t-tiles per batch elem
    const int hh  = bn * 2 + wn;          // head
    const int bh  = b * NHEAD + hh;
    size_t obase;
    if (z == 0) obase = ((size_t)bh * TSEQ + (size_t)(bm2 & 31) * 64) * DHEAD;
    else        obase = ((size_t)bh * 32 + (bm2 & 31)) * 4096;
    // DS pipe is in-order per wave (same-wave write->read, v5 Ps precedent)
#pragma unroll
    for (int c = 0; c < 8; ++c) {
        const bf16x8 cv = *(const bf16x8*)&Cs[c * 512 + l * 8];
        *(bf16x8*)(out + obase + c * 512 + l * 8) = cv;
    }
}

// out-proj: A = ctx frag-order [b][h][t>>6][4096], B = Wo frag-order; fp32 out
// Round-6 configuration: plain 2-syncthreads loop + XCD swizzle.
__global__ __launch_bounds__(256)
void gemm_out_f(const bf16_t* __restrict__ cf, const bf16_t* __restrict__ Wof,
                const float* __restrict__ bo, float* __restrict__ out)
{
    __shared__ __attribute__((aligned(16))) bf16_t As[2 * 4096];
    __shared__ __attribute__((aligned(16))) bf16_t Bs[2 * 4096];

    const int tid = threadIdx.x;
    const int l   = tid & 63;
    const int w   = tid >> 6;
    const int wm  = w >> 1, wn = w & 1;
    const int l15 = l & 15, lq = l >> 4;

    // XCD-chunked bijective remap (512 blocks, 512%8==0)
    const int lid = blockIdx.y * 8 + blockIdx.x;
    const int bm  = (lid & 7) * 8 + (lid >> 6);
    const int bn  = (lid >> 3) & 7;
    const int b   = bm >> 4;

    const bf16_t* gB[4];
    size_t aoff[4];
#pragma unroll
    for (int i = 0; i < 4; ++i) {
        const int cc = w * 4 + i;
        aoff[i] = (((size_t)b * 16) * 32 + (bm & 15) * 2 + (cc >> 3)) * 4096 + (cc & 7) * 512 + l * 8;
        gB[i] = Wof + ((size_t)(bn * 2 + (cc >> 3)) * 16) * 4096 + (cc & 7) * 512 + l * 8;
    }

    f32x4 acc[4][4] = {};

    for (int kt = 0; kt < 16; ++kt) {
#pragma unroll
        for (int i = 0; i < 4; ++i) {
            const int cc = w * 4 + i;
            gload_lds16(cf + aoff[i] + (size_t)kt * (32 * 4096), &As[cc * 512]);
            gload_lds16(gB[i] + (size_t)kt * 4096, &Bs[cc * 512]);
        }
        __syncthreads();
#pragma unroll
        for (int ks = 0; ks < 2; ++ks) {
            bf16x8 af[4], bfr[4];
#pragma unroll
            for (int mt = 0; mt < 4; ++mt)
                af[mt] = *(const bf16x8*)&As[wm * 4096 + (mt * 2 + ks) * 512 + l * 8];
#pragma unroll
            for (int nt = 0; nt < 4; ++nt)
                bfr[nt] = *(const bf16x8*)&Bs[wn * 4096 + (nt * 2 + ks) * 512 + l * 8];
#pragma unroll
            for (int mt = 0; mt < 4; ++mt)
#pragma unroll
                for (int nt = 0; nt < 4; ++nt)
                    acc[mt][nt] = __builtin_amdgcn_mfma_f32_16x16x32_bf16(af[mt], bfr[nt], acc[mt][nt], 0, 0, 0);
        }
        __syncthreads();
    }

#pragma unroll
    for (int nt = 0; nt < 4; ++nt) {
        const int gn = bn * 128 + wn * 64 + nt * 16 + l15;
        const float bv = bo[gn];
#pragma unroll
        for (int mt = 0; mt < 4; ++mt) {
            const int rb = bm * 128 + wm * 64 + mt * 16 + lq * 4;
#pragma unroll
            for (int r = 0; r < 4; ++r)
                out[(size_t)(rb + r) * NU + gn] = acc[mt][nt][r] + bv;
        }
    }
}

// ---------------- FALLBACK GEMMs (W fp32 reg-prefetch) ----------------
__global__ __launch_bounds__(256)
void gemm_qkv(const bf16_t* __restrict__ A,
              const float* __restrict__ W0, const float* __restrict__ W1, const float* __restrict__ W2,
              const float* __restrict__ B0, const float* __restrict__ B1, const float* __restrict__ B2,
              bf16_t* __restrict__ O0, bf16_t* __restrict__ O1, bf16_t* __restrict__ O2)
{
    const int z = blockIdx.z;
    const float* W    = (z == 0) ? W0 : (z == 1 ? W1 : W2);
    const float* bias = (z == 0) ? B0 : (z == 1 ? B1 : B2);
    bf16_t* out       = (z == 0) ? O0 : (z == 1 ? O1 : O2);
    const float scale = (z == 0) ? QSCALE : 1.0f;

    __shared__ __attribute__((aligned(16))) bf16_t As[128 * 64];
    __shared__ __attribute__((aligned(16))) bf16_t Bs[128 * BPAD];

    const int tid = threadIdx.x;
    const int l = tid & 63, w = tid >> 6;
    const int wm = w >> 1, wn = w & 1;
    const int l15 = l & 15, lq = l >> 4;
    const int bm = blockIdx.y, bn = blockIdx.x;
    const int srow = l >> 3, scol = (l & 7) * 8;
    const bf16_t* gA = A + (size_t)(bm * 128 + srow) * NU + scol;
    const int sr = tid >> 4, sc = (tid & 15) * 4;
    const float* gW = W + (size_t)(bn * 128 + sr) * NU + sc;

    f32x4 acc[4][4] = {};
    float4 wreg[8];
#pragma unroll
    for (int i = 0; i < 8; ++i) wreg[i] = *(const float4*)(gW + (size_t)(i * 16) * NU);

    for (int k0 = 0; k0 < NU; k0 += 64) {
#pragma unroll
        for (int i = 0; i < 4; ++i) {
            const int r0 = i * 32 + w * 8;
            gload_lds16(gA + (size_t)r0 * NU + k0, &As[r0 * 64]);
        }
#pragma unroll
        for (int i = 0; i < 8; ++i) {
            bf16x4 wb;
            wb[0] = (bf16_t)wreg[i].x; wb[1] = (bf16_t)wreg[i].y;
            wb[2] = (bf16_t)wreg[i].z; wb[3] = (bf16_t)wreg[i].w;
            *(bf16x4*)&Bs[(i * 16 + sr) * BPAD + sc] = wb;
        }
        __syncthreads();
        if (k0 + 64 < NU) {
#pragma unroll
            for (int i = 0; i < 8; ++i)
                wreg[i] = *(const float4*)(gW + (size_t)(i * 16) * NU + k0 + 64);
        }
#pragma unroll
        for (int ks = 0; ks < 2; ++ks) {
            bf16x8 af[4], bfr[4];
#pragma unroll
            for (int mt = 0; mt < 4; ++mt)
                af[mt] = *(const bf16x8*)&As[(wm * 64 + mt * 16 + l15) * 64 + ks * 32 + lq * 8];
#pragma unroll
            for (int nt = 0; nt < 4; ++nt)
                bfr[nt] = *(const bf16x8*)&Bs[(wn * 64 + nt * 16 + l15) * BPAD + ks * 32 + lq * 8];
#pragma unroll
            for (int mt = 0; mt < 4; ++mt)
#pragma unroll
                for (int nt = 0; nt < 4; ++nt)
                    acc[mt][nt] = __builtin_amdgcn_mfma_f32_16x16x32_bf16(af[mt], bfr[nt], acc[mt][nt], 0, 0, 0);
        }
        __syncthreads();
    }

#pragma unroll
    for (int nt = 0; nt < 4; ++nt) {
        const int gn = bn * 128 + wn * 64 + nt * 16 + l15;
        const float bv = bias[gn];
#pragma unroll
        for (int mt = 0; mt < 4; ++mt) {
            const int rb = bm * 128 + wm * 64 + mt * 16 + lq * 4;
#pragma unroll
            for (int r = 0; r < 4; ++r) {
                const int gm = rb + r;
                const float v = (acc[mt][nt][r] + bv) * scale;
                const int b = gm >> 11, t = gm & (TSEQ - 1);
                const int h = gn >> 6,  d = gn & 63;
                const int bh = b * NHEAD + h;
                if (z == 0)      out[((size_t)bh * TSEQ + t) * DHEAD + d] = (bf16_t)v;
                else if (z == 1) out[fragK(bh, t, d)] = (bf16_t)v;
                else             out[fragV(bh, t, d)] = (bf16_t)v;
            }
        }
    }
}

__global__ __launch_bounds__(256)
void gemm_out(const bf16_t* __restrict__ ctx, const float* __restrict__ Wo,
              const float* __restrict__ bo, float* __restrict__ out)
{
    __shared__ __attribute__((aligned(16))) bf16_t As[128 * 64];
    __shared__ __attribute__((aligned(16))) bf16_t Bs[128 * BPAD];

    const int tid = threadIdx.x;
    const int l = tid & 63, w = tid >> 6;
    const int wm = w >> 1, wn = w & 1;
    const int l15 = l & 15, lq = l >> 4;
    const int bm = blockIdx.y, bn = blockIdx.x;
    const int srow = l >> 3, scol = (l & 7) * 8;
    const int b = bm >> 4;
    const bf16_t* gA = ctx + (size_t)b * (NHEAD * TSEQ * DHEAD)
                           + (size_t)((bm & 15) * 128 + srow) * DHEAD + scol;
    const int sr = tid >> 4, sc = (tid & 15) * 4;
    const float* gW = Wo + (size_t)(bn * 128 + sr) * NU + sc;

    f32x4 acc[4][4] = {};
    float4 wreg[8];
#pragma unroll
    for (int i = 0; i < 8; ++i) wreg[i] = *(const float4*)(gW + (size_t)(i * 16) * NU);

    for (int k0 = 0; k0 < NU; k0 += 64) {
#pragma unroll
        for (int i = 0; i < 4; ++i) {
            const int r0 = i * 32 + w * 8;
            gload_lds16(gA + (size_t)r0 * DHEAD + ((size_t)k0 << 11), &As[r0 * 64]);
        }
#pragma unroll
        for (int i = 0; i < 8; ++i) {
            bf16x4 wb;
            wb[0] = (bf16_t)wreg[i].x; wb[1] = (bf16_t)wreg[i].y;
            wb[2] = (bf16_t)wreg[i].z; wb[3] = (bf16_t)wreg[i].w;
            *(bf16x4*)&Bs[(i * 16 + sr) * BPAD + sc] = wb;
        }
        __syncthreads();
        if (k0 + 64 < NU) {
#pragma unroll
            for (int i = 0; i < 8; ++i)
                wreg[i] = *(const float4*)(gW + (size_t)(i * 16) * NU + k0 + 64);
        }
#pragma unroll
        for (int ks = 0; ks < 2; ++ks) {
            bf16x8 af[4], bfr[4];
#pragma unroll
            for (int mt = 0; mt < 4; ++mt)
                af[mt] = *(const bf16x8*)&As[(wm * 64 + mt * 16 + l15) * 64 + ks * 32 + lq * 8];
#pragma unroll
            for (int nt = 0; nt < 4; ++nt)
                bfr[nt] = *(const bf16x8*)&Bs[(wn * 64 + nt * 16 + l15) * BPAD + ks * 32 + lq * 8];
#pragma unroll
            for (int mt = 0; mt < 4; ++mt)
#pragma unroll
                for (int nt = 0; nt < 4; ++nt)
                    acc[mt][nt] = __builtin_amdgcn_mfma_f32_16x16x32_bf16(af[mt], bfr[nt], acc[mt][nt], 0, 0, 0);
        }
        __syncthreads();
    }

#pragma unroll
    for (int nt = 0; nt < 4; ++nt) {
        const int gn = bn * 128 + wn * 64 + nt * 16 + l15;
        const float bv = bo[gn];
#pragma unroll
        for (int mt = 0; mt < 4; ++mt) {
            const int rb = bm * 128 + wm * 64 + mt * 16 + lq * 4;
#pragma unroll
            for (int r = 0; r < 4; ++r)
                out[(size_t)(rb + r) * NU + gn] = acc[mt][nt][r] + bv;
        }
    }
}

// ---------------- Flash attention v5: barrier-free, K/V frag global->VGPR ----------------
// Measured best of four variants (85-87us, ~885 TF effective = the plain-HIP
// 2-barrier structure ceiling). Keep frozen.
template <bool FRAGOUT>
__global__ __launch_bounds__(256, 3)
void attn_fwd(const bf16_t* __restrict__ Q, const bf16_t* __restrict__ Kf,
              const bf16_t* __restrict__ Vf, bf16_t* __restrict__ Cw)
{
    __shared__ __attribute__((aligned(16))) bf16_t Ps[4][4 * 512];   // 16 KB

    const int tid = threadIdx.x;
    const int l   = tid & 63;
    const int w   = tid >> 6;
    const int l15 = l & 15, lq = l >> 4;

    const int id = blockIdx.x;
    const int bh = (id & 7) * 8 + ((id >> 3) & 7);   // 8 bh per XCD (id%8 RR)
    const int qt = id >> 6;                          // 16 q-tiles
    const int q0 = qt * 128 + w * 32;

    const bf16_t* Qb = Q  + (size_t)bh * TSEQ * DHEAD;
    const bf16_t* Kb = Kf + (size_t)bh * TSEQ * DHEAD + l * 8;
    const bf16_t* Vb = Vf + (size_t)bh * TSEQ * DHEAD + l * 8;

    bf16x8 qf[2][2];
#pragma unroll
    for (int mt = 0; mt < 2; ++mt)
#pragma unroll
        for (int ks = 0; ks < 2; ++ks)
            qf[mt][ks] = *(const bf16x8*)(Qb + (size_t)(q0 + mt * 16 + l15) * DHEAD + ks * 32 + lq * 8);

    bf16x8 ones;
#pragma unroll
    for (int j = 0; j < 8; ++j) ones[j] = (bf16_t)1.0f;

    f32x4 cacc[2][4] = {};   // ctx^T: q = mt*16+l15, d = dt*16+lq*4+r
    f32x4 lacc[2] = {};      // MFMA row-sums

    int* PsI = (int*)&Ps[w][0];

    for (int kt = 0; kt < TSEQ / 64; ++kt) {
        const bf16_t* kb = Kb + kt * 4096;
        const bf16_t* vb = Vb + kt * 4096;

        // K fragments: direct global->VGPR (frag-order, coalesced 16B/lane)
        bf16x8 kf[8];
#pragma unroll
        for (int c = 0; c < 8; ++c) kf[c] = *(const bf16x8*)(kb + c * 512);

        // S^T[key][q] (Q pre-scaled by 0.125*log2e)
        f32x4 st[4][2] = {};
#pragma unroll
        for (int ks = 0; ks < 2; ++ks)
#pragma unroll
            for (int nt = 0; nt < 4; ++nt)
#pragma unroll
                for (int mt = 0; mt < 2; ++mt)
                    st[nt][mt] = __builtin_amdgcn_mfma_f32_16x16x32_bf16(kf[nt * 2 + ks], qf[mt][ks], st[nt][mt], 0, 0, 0);

        // P = 2^(S^T) -> pack pairs -> per-wave frag-order Ps (B-operand layout)
#pragma unroll
        for (int nt = 0; nt < 4; ++nt)
#pragma unroll
            for (int mt = 0; mt < 2; ++mt) {
                const float p0 = __builtin_amdgcn_exp2f(st[nt][mt][0]);
                const float p1 = __builtin_amdgcn_exp2f(st[nt][mt][1]);
                const float p2 = __builtin_amdgcn_exp2f(st[nt][mt][2]);
                const float p3 = __builtin_amdgcn_exp2f(st[nt][mt][3]);
                const int base = (mt * 2 + (nt >> 1)) * 256
                               + ((nt & 1) * 2 + (lq >> 1)) * 64 + l15 * 4;
                PsI[base + ((lq * 2 + 0) & 3)] = (int)pk2(p0, p1);
                PsI[base + ((lq * 2 + 1) & 3)] = (int)pk2(p2, p3);
            }

        // V fragments issued here: latency drains under the Ps lgkm wait
        bf16x8 vf[8];
#pragma unroll
        for (int c = 0; c < 8; ++c) vf[c] = *(const bf16x8*)(vb + c * 512);

        // ctx^T += V^T P^T; lsum += ones · P^T (same-wave LDS round trip, no barrier)
#pragma unroll
        for (int kv = 0; kv < 2; ++kv) {
            bf16x8 pf[2];
#pragma unroll
            for (int mt = 0; mt < 2; ++mt)
                pf[mt] = *(const bf16x8*)&Ps[w][(mt * 2 + kv) * 512 + l * 8];
#pragma unroll
            for (int mt = 0; mt < 2; ++mt) {
                lacc[mt] = __builtin_amdgcn_mfma_f32_16x16x32_bf16(ones, pf[mt], lacc[mt], 0, 0, 0);
#pragma unroll
                for (int dt = 0; dt < 4; ++dt)
                    cacc[mt][dt] = __builtin_amdgcn_mfma_f32_16x16x32_bf16(vf[dt * 2 + kv], pf[mt], cacc[mt][dt], 0, 0, 0);
            }
        }
    }

#pragma unroll
    for (int mt = 0; mt < 2; ++mt) {
        const float inv = 1.0f / lacc[mt][0];
        const int q = q0 + mt * 16 + l15;
#pragma unroll
        for (int dt = 0; dt < 4; ++dt) {
            bf16x4 cv;
#pragma unroll
            for (int r = 0; r < 4; ++r) cv[r] = (bf16_t)(cacc[mt][dt][r] * inv);
            if (FRAGOUT) {
                const int qr = q & 63;
                const size_t base = ((size_t)bh * 32 + (q >> 6)) * 4096;
                const int d0 = dt * 16 + lq * 4;
                const int addr = ((((qr >> 4) & 3) * 2 + (d0 >> 5)) << 9)
                               + (((((d0 >> 3) & 3) << 4) + (qr & 15)) << 3) + (d0 & 7);
                *(bf16x4*)&Cw[base + addr] = cv;
            } else {
                *(bf16x4*)&Cw[((size_t)bh * TSEQ + q) * DHEAD + dt * 16 + lq * 4] = cv;
            }
        }
    }
}

__global__ void diag_fill(float* out, int n, float val)
{
    int i = blockIdx.x * blockDim.x + threadIdx.x;
    if (i < n) out[i] = val;
}

extern "C" void kernel_launch(void* const* d_in, const int* in_sizes, int n_in,
                              void* d_out, int out_size, void* d_ws, size_t ws_size,
                              hipStream_t stream)
{
    const float* x  = (const float*)d_in[0];
    const float* Wq = (const float*)d_in[1];
    const float* bq = (const float*)d_in[2];
    const float* Wk = (const float*)d_in[3];
    const float* bk = (const float*)d_in[4];
    const float* Wv = (const float*)d_in[5];
    const float* bv = (const float*)d_in[6];
    const float* Wo = (const float*)d_in[7];
    const float* bo = (const float*)d_in[8];

    const size_t SLOT = (size_t)M_TOT * NU;
    const size_t WSZ  = (size_t)NU * NU;
    const size_t need_fast = (2 * SLOT + 4 * WSZ) * sizeof(bf16_t);   // 40 MB
    const size_t need_min  = 2 * SLOT * sizeof(bf16_t);               // 32 MB

    bf16_t* Qw = (bf16_t*)d_out;            // [bh][t][d], pre-scaled
    bf16_t* Kw = Qw + SLOT;                 // frag-order

    if (ws_size >= need_fast) {
        bf16_t* Xf  = (bf16_t*)d_ws;
        bf16_t* Vt  = Xf + SLOT;
        bf16_t* Wf4 = Vt + SLOT;            // Wq,Wk,Wv,Wo frag-order, contiguous
        bf16_t* Cf  = Xf;                   // ctx frag reuses x slot

        cvt_frag2<<<dim3(2048 + 4 * 256), 256, 0, stream>>>(x, Wq, Wk, Wv, Wo, Xf, Wf4);
        gemm_qkv_f<<<dim3(NU / 128, M_TOT / 128, 3), 256, 0, stream>>>(
            Xf, Wf4, Wf4 + WSZ, Wf4 + 2 * WSZ, bq, bk, bv, Qw, Kw, Vt);
        attn_fwd<true><<<dim3(1024), 256, 0, stream>>>(Qw, Kw, Vt, Cf);
        gemm_out_f<<<dim3(NU / 128, M_TOT / 128), 256, 0, stream>>>(Cf, Wf4 + 3 * WSZ, bo, (float*)d_out);
    } else if (ws_size >= need_min) {
        bf16_t* Xb = (bf16_t*)d_ws;
        bf16_t* Vt = Xb + SLOT;
        bf16_t* Cw = Xb;
        cvt_x<<<dim3(M_TOT * NU / (256 * 8)), 256, 0, stream>>>(x, Xb);
        gemm_qkv<<<dim3(NU / 128, M_TOT / 128, 3), 256, 0, stream>>>(
            Xb, Wq, Wk, Wv, bq, bk, bv, Qw, Kw, Vt);
        attn_fwd<false><<<dim3(1024), 256, 0, stream>>>(Qw, Kw, Vt, Cw);
        gemm_out<<<dim3(NU / 128, M_TOT / 128), 256, 0, stream>>>(Cw, Wo, bo, (float*)d_out);
    } else {
        diag_fill<<<(out_size + 255) / 256, 256, 0, stream>>>((float*)d_out, out_size, 9.0f);
    }
}